// Round 6
// baseline (37046.033 us; speedup 1.0000x reference)
//
#include <hip/hip_runtime.h>

#define SEQ 65536
#define IN_DIM 64
#define H 128
#define G4 512

typedef _Float16 half_t;
typedef half_t half2_t __attribute__((ext_vector_type(2)));
typedef half_t half8_t __attribute__((ext_vector_type(8)));

__device__ __forceinline__ float fast_rcp(float x) { return __builtin_amdgcn_rcpf(x); }

// no clamp: exp overflow -> inf -> rcp -> 0, the correct sigmoid limit
__device__ __forceinline__ float sigmoid_f(float x) {
    return fast_rcp(1.f + __expf(-x));
}

#if __has_builtin(__builtin_amdgcn_fdot2)
__device__ __forceinline__ float dot2(half2_t a, half2_t b, float c) {
    return __builtin_amdgcn_fdot2(a, b, c, false);
}
#else
__device__ __forceinline__ float dot2(half2_t a, half2_t b, float c) {
    return c + (float)a[0] * (float)b[0] + (float)a[1] * (float)b[1];
}
#endif

__device__ __forceinline__ half2_t pick2(half8_t v, int i0) {
    half2_t r; r[0] = v[i0]; r[1] = v[i0 + 1]; return r;
}

// 8 fp32 -> half8 (two float4 loads)
__device__ __forceinline__ half8_t cvt8(const float* p) {
    float4 a = *(const float4*)p;
    float4 b = *(const float4*)(p + 4);
    half8_t r;
    r[0] = (half_t)a.x; r[1] = (half_t)a.y; r[2] = (half_t)a.z; r[3] = (half_t)a.w;
    r[4] = (half_t)b.x; r[5] = (half_t)b.y; r[6] = (half_t)b.z; r[7] = (half_t)b.w;
    return r;
}

// quad-lane exchanges via DPP (VALU pipe). Control must be a constant -> template.
template <int CTRL>
__device__ __forceinline__ float qperm(float x) {
    return __int_as_float(
        __builtin_amdgcn_mov_dpp(__float_as_int(x), CTRL, 0xF, 0xF, true));
}
#define qx1(x)  qperm<0xB1>(x) /* quad_perm [1,0,3,2] lane^1 */
#define qx2(x)  qperm<0x4E>(x) /* quad_perm [2,3,0,1] lane^2 */

// ---------------------------------------------------------------------------
// Phase A: xg[s][j*4+g] = dot(x[s], W_ih[g*128+j]) + b_ih + b_hh
// -> quad j reads ONE broadcast float4 per step (i,f,g,o gate biases).
// ---------------------------------------------------------------------------
__global__ __launch_bounds__(256) void xg_gemm(
    const float* __restrict__ x, const float* __restrict__ Wih,
    const float* __restrict__ bih, const float* __restrict__ bhh,
    float* __restrict__ xg)
{
    long long gid = (long long)blockIdx.x * 256 + threadIdx.x;
    int s = (int)(gid >> 9);
    int rr = (int)(gid & 511);
    int j = rr >> 2, g = rr & 3;
    int row = g * H + j;
    const float* xr = x + (long long)s * IN_DIM;
    const float* wr = Wih + (long long)row * IN_DIM;
    float a0 = 0.f, a1 = 0.f, a2 = 0.f, a3 = 0.f;
#pragma unroll
    for (int k = 0; k < IN_DIM; k += 4) {
        float4 iv = *(const float4*)(xr + k);
        float4 wv = *(const float4*)(wr + k);
        a0 += wv.x * iv.x; a1 += wv.y * iv.y;
        a2 += wv.z * iv.z; a3 += wv.w * iv.w;
    }
    xg[gid] = (a0 + a1) + (a2 + a3) + bih[row] + bhh[row];
}

// ---------------------------------------------------------------------------
// Phase B: persistent 512-thread (8-wave, 2/SIMD) scan.
// Quad q = cell j; lane ql owns cols [ql*32, ql*32+32) of gate rows
// {j, 128+j, 256+j, 384+j}: 128 f16 = 64 weight VGPRs/thread. Total working
// set ~115 VGPR -- DESIGNED to fit under 128 so regalloc never spills
// (R1/R2/R3/R5 all proved pins don't beat the spill heuristic at ~200 regs).
// Step: 4x ds_read_b128 (h slice) -> 64 dot2 (8 chains) -> 2-hop quad DPP
// butterfly (all 4 lanes get all 4 gate sums) -> ALL lanes redundantly do
// activations + cell update (c per-lane; no routing, no divergence) ->
// lane 0 writes h[j] (ds_write_b16) -> raw barrier, lgkmcnt-only drain
// (depth-2 xg float4 ring rides across barriers).
// ---------------------------------------------------------------------------
__global__ __launch_bounds__(512, 2) void lstm_scan(
    const float* __restrict__ Whh, const float* __restrict__ Wlin,
    const float* __restrict__ blin, const float* __restrict__ xg,
    float* __restrict__ out)
{
    __shared__ __align__(16) half_t shbuf[2][H]; // 512 B double-buffered h
    const int tid = threadIdx.x;
    const int ql = tid & 3;
    const int j  = tid >> 2;           // cell 0..127
    const int c0 = ql * 32;

    // ---- weights: 4 gate rows x 32 cols as 16 named half8 (64 VGPRs) ----
#define LOADW(P, ROW)                                                     \
    half8_t P##0 = cvt8(Whh + (size_t)(ROW) * H + c0 + 0),                \
            P##1 = cvt8(Whh + (size_t)(ROW) * H + c0 + 8),                \
            P##2 = cvt8(Whh + (size_t)(ROW) * H + c0 + 16),               \
            P##3 = cvt8(Whh + (size_t)(ROW) * H + c0 + 24);
    LOADW(wi, j)
    LOADW(wf, 128 + j)
    LOADW(wg, 256 + j)
    LOADW(wo, 384 + j)
#undef LOADW

    const float* xgq = xg + (size_t)j * 4; // [s][j][gate] float4, quad-broadcast
    float c = 0.f;

    // xg ring: depth-2 prefetch (window ~2 steps > HBM/L3 miss latency)
    float4 xg_c = *(const float4*)(xgq + (size_t)0 * G4);
    float4 xg_n = *(const float4*)(xgq + (size_t)1 * G4);

    if (tid < H) shbuf[0][tid] = (half_t)0.f;
    __syncthreads();

#define DOT8(ACC, WV, HV)                                                 \
    ACC = dot2(pick2(WV, 0), pick2(HV, 0), ACC);                          \
    ACC = dot2(pick2(WV, 2), pick2(HV, 2), ACC);                          \
    ACC = dot2(pick2(WV, 4), pick2(HV, 4), ACC);                          \
    ACC = dot2(pick2(WV, 6), pick2(HV, 6), ACC);
#define QRED(X) X += qx1(X); X += qx2(X);

#define STEP(RB, WB, T)                                                   \
    {                                                                     \
        const half8_t* hp = (const half8_t*)&shbuf[RB][c0];               \
        half8_t h0 = hp[0], h1 = hp[1], h2 = hp[2], h3 = hp[3];           \
        int tp = (T) + 2; if (tp > SEQ - 1) tp = SEQ - 1;                 \
        float4 xg_p = *(const float4*)(xgq + (size_t)tp * G4);            \
        float ai0 = 0.f, ai1 = 0.f, af0 = 0.f, af1 = 0.f;                 \
        float ag0 = 0.f, ag1 = 0.f, ao0 = 0.f, ao1 = 0.f;                 \
        DOT8(ai0, wi0, h0) DOT8(ai1, wi1, h1)                             \
        DOT8(ai0, wi2, h2) DOT8(ai1, wi3, h3)                             \
        DOT8(af0, wf0, h0) DOT8(af1, wf1, h1)                             \
        DOT8(af0, wf2, h2) DOT8(af1, wf3, h3)                             \
        DOT8(ag0, wg0, h0) DOT8(ag1, wg1, h1)                             \
        DOT8(ag0, wg2, h2) DOT8(ag1, wg3, h3)                             \
        DOT8(ao0, wo0, h0) DOT8(ao1, wo1, h1)                             \
        DOT8(ao0, wo2, h2) DOT8(ao1, wo3, h3)                             \
        float si = ai0 + ai1, sf = af0 + af1;                             \
        float sg = ag0 + ag1, so = ao0 + ao1;                             \
        QRED(si) QRED(sf) QRED(sg) QRED(so)                               \
        float gi = sigmoid_f(si + xg_c.x);                                \
        float gf = sigmoid_f(sf + xg_c.y);                                \
        float ug = sg + xg_c.z;                                           \
        float s2 = sigmoid_f(ug + ug);                                    \
        float gg = s2 + s2 - 1.f;        /* tanh = 2*sig(2x)-1 */         \
        float go = sigmoid_f(so + xg_c.w);                                \
        c = gf * c + gi * gg;                                             \
        float sc = sigmoid_f(c + c);                                      \
        float th = sc + sc - 1.f;                                         \
        float hh = go * th;                                               \
        if (ql == 0) shbuf[WB][j] = (half_t)hh;                           \
        asm volatile("s_waitcnt lgkmcnt(0)" ::: "memory");                \
        __builtin_amdgcn_s_barrier();                                     \
        __builtin_amdgcn_sched_barrier(0);                                \
        xg_c = xg_n; xg_n = xg_p;                                         \
    }

    for (int t = 0; t < SEQ; t += 2) {
        STEP(0, 1, t)
        STEP(1, 0, t + 1)
    }
#undef STEP
#undef QRED
#undef DOT8

    // h(SEQ) in shbuf[0]; one wave reduces the linear head.
    if (tid < 64) {
        float p = (float)shbuf[0][tid] * Wlin[tid] +
                  (float)shbuf[0][tid + 64] * Wlin[tid + 64];
#pragma unroll
        for (int off = 32; off > 0; off >>= 1) p += __shfl_down(p, off);
        if (tid == 0) out[0] = sigmoid_f(p + blin[0]);
    }
}

// ---------------------------------------------------------------------------
// Fallback (ws too small): round-2 kernel, known correct, no scratch needed.
// ---------------------------------------------------------------------------
__global__ __launch_bounds__(512, 2) void lstm_scan_fb(
    const float* __restrict__ x, const float* __restrict__ Wih,
    const float* __restrict__ Whh, const float* __restrict__ bih,
    const float* __restrict__ bhh, const float* __restrict__ Wlin,
    const float* __restrict__ blin, float* __restrict__ out)
{
    __shared__ __align__(16) half_t sh_h[H];
    __shared__ __align__(16) float  sh_g[G4];
    const int row = threadIdx.x;
    const float* wrow = Whh + (long long)row * H;

    half8_t w0  = cvt8(wrow + 0),   w1  = cvt8(wrow + 8);
    half8_t w2  = cvt8(wrow + 16),  w3  = cvt8(wrow + 24);
    half8_t w4  = cvt8(wrow + 32),  w5  = cvt8(wrow + 40);
    half8_t w6  = cvt8(wrow + 48),  w7  = cvt8(wrow + 56);
    half8_t w8  = cvt8(wrow + 64),  w9  = cvt8(wrow + 72);
    half8_t w10 = cvt8(wrow + 80),  w11 = cvt8(wrow + 88);
    half8_t w12 = cvt8(wrow + 96),  w13 = cvt8(wrow + 104);
    half8_t w14 = cvt8(wrow + 112), w15 = cvt8(wrow + 120);

    const float bsum = bih[row] + bhh[row];
    float c = 0.f;
    if (row < H) sh_h[row] = (half_t)0.f;

    float xg_cur;
    {
        float a = bsum;
        const float* wir = Wih + (long long)row * IN_DIM;
#pragma unroll
        for (int k = 0; k < IN_DIM; k += 4) {
            float4 iv = *(const float4*)(x + k);
            float4 wv = *(const float4*)(wir + k);
            a += wv.x * iv.x + wv.y * iv.y + wv.z * iv.z + wv.w * iv.w;
        }
        xg_cur = a;
    }
    const bool is_g = (row >= 2 * H) && (row < 3 * H);
    __syncthreads();

    const half8_t* hch = (const half8_t*)sh_h;

    for (int t = 0; t < SEQ; ++t) {
        float xg_nxt = 0.f;
        if (t + 1 < SEQ) {
            const float* xr = x + (size_t)(t + 1) * IN_DIM;
            const float* wir = Wih + (long long)row * IN_DIM;
            float a = bsum;
#pragma unroll
            for (int k = 0; k < IN_DIM; k += 4) {
                float4 iv = *(const float4*)(xr + k);
                float4 wv = *(const float4*)(wir + k);
                a += wv.x * iv.x + wv.y * iv.y + wv.z * iv.z + wv.w * iv.w;
            }
            xg_nxt = a;
        }
        float a0 = 0.f, a1 = 0.f, a2 = 0.f, a3 = 0.f;
#define DOTC(WV, CI)                                                     \
        {   half8_t hv = hch[CI];                                        \
            a0 = dot2(pick2(WV, 0), pick2(hv, 0), a0);                   \
            a1 = dot2(pick2(WV, 2), pick2(hv, 2), a1);                   \
            a2 = dot2(pick2(WV, 4), pick2(hv, 4), a2);                   \
            a3 = dot2(pick2(WV, 6), pick2(hv, 6), a3); }
        DOTC(w0, 0)  DOTC(w1, 1)  DOTC(w2, 2)   DOTC(w3, 3)
        DOTC(w4, 4)  DOTC(w5, 5)  DOTC(w6, 6)   DOTC(w7, 7)
        DOTC(w8, 8)  DOTC(w9, 9)  DOTC(w10, 10) DOTC(w11, 11)
        DOTC(w12, 12) DOTC(w13, 13) DOTC(w14, 14) DOTC(w15, 15)
#undef DOTC
        float pre = xg_cur + ((a0 + a1) + (a2 + a3));
        float gv;
        if (is_g) {
            float s = sigmoid_f(pre + pre);
            gv = s + s - 1.f;
        } else {
            gv = sigmoid_f(pre);
        }
        sh_g[row] = gv;
        __syncthreads();
        if (row >= 3 * H) {
            int jj = row - 3 * H;
            float ig = sh_g[jj];
            float fg = sh_g[H + jj];
            float gg = sh_g[2 * H + jj];
            c = fg * c + ig * gg;
            float s = sigmoid_f(c + c);
            sh_h[jj] = (half_t)(gv * (s + s - 1.f));
        }
        __syncthreads();
        xg_cur = xg_nxt;
    }

    if (row < 64) {
        float p = (float)sh_h[row] * Wlin[row] +
                  (float)sh_h[row + 64] * Wlin[row + 64];
#pragma unroll
        for (int off = 32; off > 0; off >>= 1) p += __shfl_down(p, off);
        if (row == 0) out[0] = sigmoid_f(p + blin[0]);
    }
}

extern "C" void kernel_launch(void* const* d_in, const int* in_sizes, int n_in,
                              void* d_out, int out_size, void* d_ws, size_t ws_size,
                              hipStream_t stream)
{
    const float* x    = (const float*)d_in[0];
    const float* Wih  = (const float*)d_in[1];
    const float* Whh  = (const float*)d_in[2];
    const float* bih  = (const float*)d_in[3];
    const float* bhh  = (const float*)d_in[4];
    const float* Wlin = (const float*)d_in[5];
    const float* blin = (const float*)d_in[6];
    float* out = (float*)d_out;

    const size_t need = (size_t)SEQ * G4 * sizeof(float); // 128 MB
    if (ws_size >= need) {
        float* xg = (float*)d_ws;
        xg_gemm<<<(SEQ * G4) / 256, 256, 0, stream>>>(x, Wih, bih, bhh, xg);
        lstm_scan<<<1, 512, 0, stream>>>(Whh, Wlin, blin, xg, out);
    } else {
        lstm_scan_fb<<<1, 512, 0, stream>>>(x, Wih, Whh, bih, bhh, Wlin,
                                            blin, out);
    }
}

// Round 7
// 37036.127 us; speedup vs baseline: 1.0003x; 1.0003x over previous
//
#include <hip/hip_runtime.h>

#define SEQ 65536
#define IN_DIM 64
#define H 128
#define G4 512

typedef _Float16 half_t;
typedef half_t half2_t __attribute__((ext_vector_type(2)));
typedef half_t half8_t __attribute__((ext_vector_type(8)));

__device__ __forceinline__ float fast_rcp(float x) { return __builtin_amdgcn_rcpf(x); }

// no clamp: exp overflow -> inf -> rcp -> 0, the correct sigmoid limit
__device__ __forceinline__ float sigmoid_f(float x) {
    return fast_rcp(1.f + __expf(-x));
}

#if __has_builtin(__builtin_amdgcn_fdot2)
__device__ __forceinline__ float dot2(half2_t a, half2_t b, float c) {
    return __builtin_amdgcn_fdot2(a, b, c, false);
}
#else
__device__ __forceinline__ float dot2(half2_t a, half2_t b, float c) {
    return c + (float)a[0] * (float)b[0] + (float)a[1] * (float)b[1];
}
#endif

__device__ __forceinline__ half2_t pick2(half8_t v, int i0) {
    half2_t r; r[0] = v[i0]; r[1] = v[i0 + 1]; return r;
}

// 8 fp32 -> half8 (two float4 loads)
__device__ __forceinline__ half8_t cvt8(const float* p) {
    float4 a = *(const float4*)p;
    float4 b = *(const float4*)(p + 4);
    half8_t r;
    r[0] = (half_t)a.x; r[1] = (half_t)a.y; r[2] = (half_t)a.z; r[3] = (half_t)a.w;
    r[4] = (half_t)b.x; r[5] = (half_t)b.y; r[6] = (half_t)b.z; r[7] = (half_t)b.w;
    return r;
}

// quad-lane exchanges via DPP (VALU pipe). Control must be a constant -> template.
template <int CTRL>
__device__ __forceinline__ float qperm(float x) {
    return __int_as_float(
        __builtin_amdgcn_mov_dpp(__float_as_int(x), CTRL, 0xF, 0xF, true));
}
#define qx1(x)  qperm<0xB1>(x) /* quad_perm [1,0,3,2] lane^1 */
#define qx2(x)  qperm<0x4E>(x) /* quad_perm [2,3,0,1] lane^2 */

// ---------------------------------------------------------------------------
// Phase A: xg[s][j*4+g] = dot(x[s], W_ih[g*128+j]) + b_ih + b_hh
// -> quad j reads ONE broadcast float4 per step (i,f,g,o gate biases).
// ---------------------------------------------------------------------------
__global__ __launch_bounds__(256) void xg_gemm(
    const float* __restrict__ x, const float* __restrict__ Wih,
    const float* __restrict__ bih, const float* __restrict__ bhh,
    float* __restrict__ xg)
{
    long long gid = (long long)blockIdx.x * 256 + threadIdx.x;
    int s = (int)(gid >> 9);
    int rr = (int)(gid & 511);
    int j = rr >> 2, g = rr & 3;
    int row = g * H + j;
    const float* xr = x + (long long)s * IN_DIM;
    const float* wr = Wih + (long long)row * IN_DIM;
    float a0 = 0.f, a1 = 0.f, a2 = 0.f, a3 = 0.f;
#pragma unroll
    for (int k = 0; k < IN_DIM; k += 4) {
        float4 iv = *(const float4*)(xr + k);
        float4 wv = *(const float4*)(wr + k);
        a0 += wv.x * iv.x; a1 += wv.y * iv.y;
        a2 += wv.z * iv.z; a3 += wv.w * iv.w;
    }
    xg[gid] = (a0 + a1) + (a2 + a3) + bih[row] + bhh[row];
}

// ---------------------------------------------------------------------------
// Phase B: persistent 512-thread (8-wave, 2/SIMD) scan.
// Geometry IDENTICAL to round 6. Single change: amdgpu_waves_per_eu(2,2)
// pins the scheduler's occupancy TARGET to 2 waves/EU (256-VGPR budget).
// R2/R3/R5/R6 all show the scheduler demoting loop-invariant weights to
// chase the 8-waves/EU (64-VGPR) tier it could theoretically reach with
// multiple resident blocks (it can't know grid=1). launch_bounds' 2nd arg
// only sets the MIN; this attribute clamps the MAX.
// ---------------------------------------------------------------------------
__attribute__((amdgpu_waves_per_eu(2, 2)))
__global__ __launch_bounds__(512) void lstm_scan(
    const float* __restrict__ Whh, const float* __restrict__ Wlin,
    const float* __restrict__ blin, const float* __restrict__ xg,
    float* __restrict__ out)
{
    __shared__ __align__(16) half_t shbuf[2][H]; // 512 B double-buffered h
    const int tid = threadIdx.x;
    const int ql = tid & 3;
    const int j  = tid >> 2;           // cell 0..127
    const int c0 = ql * 32;

    // ---- weights: 4 gate rows x 32 cols as 16 named half8 (64 VGPRs) ----
#define LOADW(P, ROW)                                                     \
    half8_t P##0 = cvt8(Whh + (size_t)(ROW) * H + c0 + 0),                \
            P##1 = cvt8(Whh + (size_t)(ROW) * H + c0 + 8),                \
            P##2 = cvt8(Whh + (size_t)(ROW) * H + c0 + 16),               \
            P##3 = cvt8(Whh + (size_t)(ROW) * H + c0 + 24);
    LOADW(wi, j)
    LOADW(wf, 128 + j)
    LOADW(wg, 256 + j)
    LOADW(wo, 384 + j)
#undef LOADW

    const float* xgq = xg + (size_t)j * 4; // [s][j][gate] float4, quad-broadcast
    float c = 0.f;

    // xg ring: depth-2 prefetch (window ~2 steps > HBM/L3 miss latency)
    float4 xg_c = *(const float4*)(xgq + (size_t)0 * G4);
    float4 xg_n = *(const float4*)(xgq + (size_t)1 * G4);

    if (tid < H) shbuf[0][tid] = (half_t)0.f;
    __syncthreads();

#define DOT8(ACC, WV, HV)                                                 \
    ACC = dot2(pick2(WV, 0), pick2(HV, 0), ACC);                          \
    ACC = dot2(pick2(WV, 2), pick2(HV, 2), ACC);                          \
    ACC = dot2(pick2(WV, 4), pick2(HV, 4), ACC);                          \
    ACC = dot2(pick2(WV, 6), pick2(HV, 6), ACC);
#define QRED(X) X += qx1(X); X += qx2(X);

#define STEP(RB, WB, T)                                                   \
    {                                                                     \
        const half8_t* hp = (const half8_t*)&shbuf[RB][c0];               \
        half8_t h0 = hp[0], h1 = hp[1], h2 = hp[2], h3 = hp[3];           \
        int tp = (T) + 2; if (tp > SEQ - 1) tp = SEQ - 1;                 \
        float4 xg_p = *(const float4*)(xgq + (size_t)tp * G4);            \
        float ai0 = 0.f, ai1 = 0.f, af0 = 0.f, af1 = 0.f;                 \
        float ag0 = 0.f, ag1 = 0.f, ao0 = 0.f, ao1 = 0.f;                 \
        DOT8(ai0, wi0, h0) DOT8(ai1, wi1, h1)                             \
        DOT8(ai0, wi2, h2) DOT8(ai1, wi3, h3)                             \
        DOT8(af0, wf0, h0) DOT8(af1, wf1, h1)                             \
        DOT8(af0, wf2, h2) DOT8(af1, wf3, h3)                             \
        DOT8(ag0, wg0, h0) DOT8(ag1, wg1, h1)                             \
        DOT8(ag0, wg2, h2) DOT8(ag1, wg3, h3)                             \
        DOT8(ao0, wo0, h0) DOT8(ao1, wo1, h1)                             \
        DOT8(ao0, wo2, h2) DOT8(ao1, wo3, h3)                             \
        float si = ai0 + ai1, sf = af0 + af1;                             \
        float sg = ag0 + ag1, so = ao0 + ao1;                             \
        QRED(si) QRED(sf) QRED(sg) QRED(so)                               \
        float gi = sigmoid_f(si + xg_c.x);                                \
        float gf = sigmoid_f(sf + xg_c.y);                                \
        float ug = sg + xg_c.z;                                           \
        float s2 = sigmoid_f(ug + ug);                                    \
        float gg = s2 + s2 - 1.f;        /* tanh = 2*sig(2x)-1 */         \
        float go = sigmoid_f(so + xg_c.w);                                \
        c = gf * c + gi * gg;                                             \
        float sc = sigmoid_f(c + c);                                      \
        float th = sc + sc - 1.f;                                         \
        float hh = go * th;                                               \
        if (ql == 0) shbuf[WB][j] = (half_t)hh;                           \
        asm volatile("s_waitcnt lgkmcnt(0)" ::: "memory");                \
        __builtin_amdgcn_s_barrier();                                     \
        __builtin_amdgcn_sched_barrier(0);                                \
        xg_c = xg_n; xg_n = xg_p;                                         \
    }

    for (int t = 0; t < SEQ; t += 2) {
        STEP(0, 1, t)
        STEP(1, 0, t + 1)
    }
#undef STEP
#undef QRED
#undef DOT8

    // h(SEQ) in shbuf[0]; one wave reduces the linear head.
    if (tid < 64) {
        float p = (float)shbuf[0][tid] * Wlin[tid] +
                  (float)shbuf[0][tid + 64] * Wlin[tid + 64];
#pragma unroll
        for (int off = 32; off > 0; off >>= 1) p += __shfl_down(p, off);
        if (tid == 0) out[0] = sigmoid_f(p + blin[0]);
    }
}

// ---------------------------------------------------------------------------
// Fallback (ws too small): round-2 kernel, known correct, no scratch needed.
// ---------------------------------------------------------------------------
__global__ __launch_bounds__(512, 2) void lstm_scan_fb(
    const float* __restrict__ x, const float* __restrict__ Wih,
    const float* __restrict__ Whh, const float* __restrict__ bih,
    const float* __restrict__ bhh, const float* __restrict__ Wlin,
    const float* __restrict__ blin, float* __restrict__ out)
{
    __shared__ __align__(16) half_t sh_h[H];
    __shared__ __align__(16) float  sh_g[G4];
    const int row = threadIdx.x;
    const float* wrow = Whh + (long long)row * H;

    half8_t w0  = cvt8(wrow + 0),   w1  = cvt8(wrow + 8);
    half8_t w2  = cvt8(wrow + 16),  w3  = cvt8(wrow + 24);
    half8_t w4  = cvt8(wrow + 32),  w5  = cvt8(wrow + 40);
    half8_t w6  = cvt8(wrow + 48),  w7  = cvt8(wrow + 56);
    half8_t w8  = cvt8(wrow + 64),  w9  = cvt8(wrow + 72);
    half8_t w10 = cvt8(wrow + 80),  w11 = cvt8(wrow + 88);
    half8_t w12 = cvt8(wrow + 96),  w13 = cvt8(wrow + 104);
    half8_t w14 = cvt8(wrow + 112), w15 = cvt8(wrow + 120);

    const float bsum = bih[row] + bhh[row];
    float c = 0.f;
    if (row < H) sh_h[row] = (half_t)0.f;

    float xg_cur;
    {
        float a = bsum;
        const float* wir = Wih + (long long)row * IN_DIM;
#pragma unroll
        for (int k = 0; k < IN_DIM; k += 4) {
            float4 iv = *(const float4*)(x + k);
            float4 wv = *(const float4*)(wir + k);
            a += wv.x * iv.x + wv.y * iv.y + wv.z * iv.z + wv.w * iv.w;
        }
        xg_cur = a;
    }
    const bool is_g = (row >= 2 * H) && (row < 3 * H);
    __syncthreads();

    const half8_t* hch = (const half8_t*)sh_h;

    for (int t = 0; t < SEQ; ++t) {
        float xg_nxt = 0.f;
        if (t + 1 < SEQ) {
            const float* xr = x + (size_t)(t + 1) * IN_DIM;
            const float* wir = Wih + (long long)row * IN_DIM;
            float a = bsum;
#pragma unroll
            for (int k = 0; k < IN_DIM; k += 4) {
                float4 iv = *(const float4*)(xr + k);
                float4 wv = *(const float4*)(wir + k);
                a += wv.x * iv.x + wv.y * iv.y + wv.z * iv.z + wv.w * iv.w;
            }
            xg_nxt = a;
        }
        float a0 = 0.f, a1 = 0.f, a2 = 0.f, a3 = 0.f;
#define DOTC(WV, CI)                                                     \
        {   half8_t hv = hch[CI];                                        \
            a0 = dot2(pick2(WV, 0), pick2(hv, 0), a0);                   \
            a1 = dot2(pick2(WV, 2), pick2(hv, 2), a1);                   \
            a2 = dot2(pick2(WV, 4), pick2(hv, 4), a2);                   \
            a3 = dot2(pick2(WV, 6), pick2(hv, 6), a3); }
        DOTC(w0, 0)  DOTC(w1, 1)  DOTC(w2, 2)   DOTC(w3, 3)
        DOTC(w4, 4)  DOTC(w5, 5)  DOTC(w6, 6)   DOTC(w7, 7)
        DOTC(w8, 8)  DOTC(w9, 9)  DOTC(w10, 10) DOTC(w11, 11)
        DOTC(w12, 12) DOTC(w13, 13) DOTC(w14, 14) DOTC(w15, 15)
#undef DOTC
        float pre = xg_cur + ((a0 + a1) + (a2 + a3));
        float gv;
        if (is_g) {
            float s = sigmoid_f(pre + pre);
            gv = s + s - 1.f;
        } else {
            gv = sigmoid_f(pre);
        }
        sh_g[row] = gv;
        __syncthreads();
        if (row >= 3 * H) {
            int jj = row - 3 * H;
            float ig = sh_g[jj];
            float fg = sh_g[H + jj];
            float gg = sh_g[2 * H + jj];
            c = fg * c + ig * gg;
            float s = sigmoid_f(c + c);
            sh_h[jj] = (half_t)(gv * (s + s - 1.f));
        }
        __syncthreads();
        xg_cur = xg_nxt;
    }

    if (row < 64) {
        float p = (float)sh_h[row] * Wlin[row] +
                  (float)sh_h[row + 64] * Wlin[row + 64];
#pragma unroll
        for (int off = 32; off > 0; off >>= 1) p += __shfl_down(p, off);
        if (row == 0) out[0] = sigmoid_f(p + blin[0]);
    }
}

extern "C" void kernel_launch(void* const* d_in, const int* in_sizes, int n_in,
                              void* d_out, int out_size, void* d_ws, size_t ws_size,
                              hipStream_t stream)
{
    const float* x    = (const float*)d_in[0];
    const float* Wih  = (const float*)d_in[1];
    const float* Whh  = (const float*)d_in[2];
    const float* bih  = (const float*)d_in[3];
    const float* bhh  = (const float*)d_in[4];
    const float* Wlin = (const float*)d_in[5];
    const float* blin = (const float*)d_in[6];
    float* out = (float*)d_out;

    const size_t need = (size_t)SEQ * G4 * sizeof(float); // 128 MB
    if (ws_size >= need) {
        float* xg = (float*)d_ws;
        xg_gemm<<<(SEQ * G4) / 256, 256, 0, stream>>>(x, Wih, bih, bhh, xg);
        lstm_scan<<<1, 512, 0, stream>>>(Whh, Wlin, blin, xg, out);
    } else {
        lstm_scan_fb<<<1, 512, 0, stream>>>(x, Wih, Whh, bih, bhh, Wlin,
                                            blin, out);
    }
}